// Round 5
// baseline (85.342 us; speedup 1.0000x reference)
//
#include <hip/hip_runtime.h>

// NS=256, NT=16384, D=3, H=64. g0(feat), g1(feat) are scalar functions of the
// single invariant feat=ln(d/L) -> 64-channel Pade net collapsed to a table.
// Nearest-neighbor lookup (8B ds_read_b64) at 2x resolution instead of lerp
// (16B b128): halves LDS gather bytes, the in-kernel bottleneck. Block = 64
// targets x 8 source-groups (512 thr), LDS reduction, one float4 store/target.
#define NSRC 256
#define NTGT 16384
#define NH   64
#define TAB_N 6144                       // entries; 48 KB LDS as float2
constexpr float TAB_LO = -5.0f;          // feat range: data ~[-4.3, 2.4]
constexpr float TAB_HI =  2.6f;
constexpr float TAB_STEP     = (TAB_HI - TAB_LO) / (float)(TAB_N - 1);
constexpr float TAB_INV_STEP = 1.0f / TAB_STEP;
constexpr float EPS2 = 1e-8f * 1e-8f;
constexpr float LN2  = 0.6931471805599453f;
constexpr int   TPB    = 512;
constexpr int   TGT_B  = 64;             // targets per block (= wave size)
constexpr int   NGRP   = 8;              // source groups per block
constexpr int   SG     = NSRC / NGRP;    // sources per group = 32

__global__ __launch_bounds__(256)
void build_table(const float* __restrict__ W1, const float* __restrict__ b1,
                 const float* __restrict__ pa, const float* __restrict__ pb,
                 const float* __restrict__ W2, const float* __restrict__ b2,
                 float2* __restrict__ tab)
{
    const int i = blockIdx.x * 256 + threadIdx.x;
    if (i >= TAB_N) return;
    const float feat = TAB_LO + (float)i * TAB_STEP;
    float g0 = b2[0], g1 = b2[1];        // b2 folded into the table
    for (int h = 0; h < NH; ++h) {
        const float x   = fmaf(feat, W1[h], b1[h]);
        const float x2  = x * x;
        const float num = fmaf(x2, pa[h * 3 + 2], fmaf(x, pa[h * 3 + 1], pa[h * 3 + 0]));
        const float den = 1.0f + fabsf(fmaf(x2, pb[h * 2 + 1], x * pb[h * 2 + 0]));
        const float g   = num * __builtin_amdgcn_rcpf(den);   // den >= 1
        g0 = fmaf(g, W2[h * 2 + 0], g0);
        g1 = fmaf(g, W2[h * 2 + 1], g1);
    }
    tab[i] = make_float2(g0, g1);
}

__global__ __launch_bounds__(TPB)
void field_kernel(const float* __restrict__ refL,
                  const float* __restrict__ src,   // [NSRC,3]
                  const float* __restrict__ tgt,   // [NTGT,3]
                  const float* __restrict__ str,   // [NSRC]
                  const float4* __restrict__ gtab, // table as float4[TAB_N/2]
                  float* __restrict__ out)         // [NTGT,4]
{
    __shared__ float4 tab4[TAB_N / 2];   // 48 KB; aliased as float2[TAB_N]
    __shared__ float4 part[NGRP][TGT_B]; // 8 KB reduction buffer
    const float2* tab = (const float2*)tab4;

    for (int j = threadIdx.x; j < TAB_N / 2; j += TPB) tab4[j] = gtab[j];
    __syncthreads();

    const int jt = threadIdx.x & (TGT_B - 1);                        // target lane
    const int g  = __builtin_amdgcn_readfirstlane(threadIdx.x >> 6); // uniform group
    const int t  = blockIdx.x * TGT_B + jt;
    const int sb = g * SG;

    const float tx = tgt[t * 3 + 0];
    const float ty = tgt[t * 3 + 1];
    const float tz = tgt[t * 3 + 2];
    const float logL = __builtin_amdgcn_logf(refL[0]) * LN2;
    // nearest index = round((0.5*ln(d2)-lnL-LO)/STEP) = trunc(log2(d2)*K1+K2c)
    const float K1  = 0.5f * LN2 * TAB_INV_STEP;
    const float K2c = (-logL - TAB_LO) * TAB_INV_STEP + 0.5f;

    float acc0 = 0.f, ax = 0.f, ay = 0.f, az = 0.f;
    #pragma unroll 16
    for (int i = 0; i < SG; ++i) {
        const int s = sb + i;                                  // wave-uniform -> s_load
        const float rx = tx - src[s * 3 + 0];
        const float ry = ty - src[s * 3 + 1];
        const float rz = tz - src[s * 3 + 2];
        const float d2 = fmaf(rx, rx, fmaf(ry, ry, fmaf(rz, rz, EPS2)));
        const float idxf = fmaf(__builtin_amdgcn_logf(d2), K1, K2c);
        const int ii = (int)fminf(fmaxf(idxf, 0.0f), (float)(TAB_N - 1)); // med3+cvt
        const float2 e = tab[ii];                              // one ds_read_b64
        const float invd = __builtin_amdgcn_rsqf(d2);
        const float w = str[s];
        acc0 = fmaf(e.x, w, acc0);
        const float c = e.y * w * invd;
        ax = fmaf(c, rx, ax);
        ay = fmaf(c, ry, ay);
        az = fmaf(c, rz, az);
    }

    part[g][jt] = make_float4(acc0, ax, ay, az);
    __syncthreads();

    if (threadIdx.x < TGT_B) {
        float4 r = part[0][jt];
        #pragma unroll
        for (int k = 1; k < NGRP; ++k) {
            const float4 p = part[k][jt];
            r.x += p.x; r.y += p.y; r.z += p.z; r.w += p.w;
        }
        ((float4*)out)[t] = r;                                 // coalesced dwordx4
    }
}

extern "C" void kernel_launch(void* const* d_in, const int* in_sizes, int n_in,
                              void* d_out, int out_size, void* d_ws, size_t ws_size,
                              hipStream_t stream) {
    const float* refL = (const float*)d_in[0];
    const float* src  = (const float*)d_in[1];
    const float* tgt  = (const float*)d_in[2];
    const float* str  = (const float*)d_in[3];
    const float* W1   = (const float*)d_in[4];
    const float* b1   = (const float*)d_in[5];
    const float* pa   = (const float*)d_in[6];
    const float* pb   = (const float*)d_in[7];
    const float* W2   = (const float*)d_in[8];
    const float* b2   = (const float*)d_in[9];
    float*  out = (float*)d_out;
    float2* tab = (float2*)d_ws;         // TAB_N*8 = 49,152 B of ws

    build_table<<<dim3(TAB_N / 256), dim3(256), 0, stream>>>(
        W1, b1, pa, pb, W2, b2, tab);

    field_kernel<<<dim3(NTGT / TGT_B), dim3(TPB), 0, stream>>>(
        refL, src, tgt, str, (const float4*)tab, out);
}